// Round 1
// baseline (1505.171 us; speedup 1.0000x reference)
//
#include <hip/hip_runtime.h>

typedef __bf16 bf16;
typedef __bf16 bf16x8 __attribute__((ext_vector_type(8)));
typedef __bf16 bf16x4 __attribute__((ext_vector_type(4)));
typedef float  f32x4  __attribute__((ext_vector_type(4)));

// Problem constants
// B=32, N=1024, DIM=1152, H=12, KV=4, D=96, G=3, P=3, LS=32

static __device__ __forceinline__ float load_any(const void* p, size_t i, int isbf) {
  return isbf ? (float)((const bf16*)p)[i] : ((const float*)p)[i];
}

// ---------------- dtype detect ----------------
// If inputs are bf16, low 16 bits of each dword are a bf16 value whose exponent
// field sits near bias 127 for N(0,1)-scale data. If fp32, low 16 bits are
// uniform mantissa bits (P(exp-field in [100,140]) ~ 16%). 256 samples decide.
__global__ void k_detect(const unsigned int* __restrict__ x, int* __restrict__ flag) {
  __shared__ int cnt[256];
  unsigned int w = x[(size_t)threadIdx.x * 65536u + 123u];
  unsigned int lo = w & 0xffffu;
  int e = (int)((lo >> 7) & 0xffu);
  cnt[threadIdx.x] = (lo == 0u) || (e >= 100 && e <= 140);
  __syncthreads();
  for (int s = 128; s > 0; s >>= 1) {
    if ((int)threadIdx.x < s) cnt[threadIdx.x] += cnt[threadIdx.x + s];
    __syncthreads();
  }
  if (threadIdx.x == 0) *flag = (cnt[0] >= 128) ? 1 : 0;
}

// ---------------- small params -> fp32 ----------------
// pbuf layout: [0,1152) wq_b | [1152,1920) wkv_b | [1920,5376) dwc_w(384*9)
//              | [5376,5760) dwc_b | [5760,6912) proj_b
__global__ void k_prep(const void* wq_b, const void* wkv_b, const void* dwc_w,
                       const void* dwc_b, const void* proj_b,
                       float* __restrict__ pbuf, const int* __restrict__ flagp) {
  int isbf = *flagp;
  int i = blockIdx.x * 256 + threadIdx.x;
  if (i >= 6912) return;
  float v;
  if (i < 1152)      v = load_any(wq_b,   i,        isbf);
  else if (i < 1920) v = load_any(wkv_b,  i - 1152, isbf);
  else if (i < 5376) v = load_any(dwc_w,  i - 1920, isbf);
  else if (i < 5760) v = load_any(dwc_b,  i - 5376, isbf);
  else               v = load_any(proj_b, i - 5760, isbf);
  pbuf[i] = v;
}

// ---------------- weight transpose -> bf16 [out][in] ----------------
__global__ __launch_bounds__(256) void k_transpose(const void* __restrict__ in,
    bf16* __restrict__ out, int R, int C, const int* __restrict__ flagp) {
  int isbf = *flagp;
  __shared__ bf16 tile[32][33];
  int c0 = blockIdx.x * 32, r0 = blockIdx.y * 32;
  int tx = threadIdx.x & 31, ty = threadIdx.x >> 5;   // 32 x 8
  for (int i = ty; i < 32; i += 8) {
    int r = r0 + i, c = c0 + tx;
    float v = (r < R && c < C) ? load_any(in, (size_t)r * C + c, isbf) : 0.f;
    tile[i][tx] = (bf16)v;
  }
  __syncthreads();
  for (int i = ty; i < 32; i += 8) {
    int c = c0 + i, r = r0 + tx;
    if (c < C && r < R) out[(size_t)c * R + r] = tile[tx][i];
  }
}

// ---------------- x ingest -> bf16 ----------------
__global__ void k_ingest(const void* __restrict__ x, bf16* __restrict__ xb,
                         const int* __restrict__ flagp) {
  int isbf = *flagp;
  size_t i = (size_t)blockIdx.x * 256 + threadIdx.x;
  if (i >= (size_t)37748736) return;
  xb[i] = isbf ? ((const bf16*)x)[i] : (bf16)((const float*)x)[i];
}

// ---------------- MFMA GEMM: C[M,N] = A[M,K] @ Bt[N,K]^T + bias ----------------
// 128x128 tile, BK=32, 4 waves each owning a 64x64 quadrant (4x4 of 16x16 mfma).
// LDS stride padded to 40 elems (80 B) -> <=2-way bank aliasing on ds_read_b128.
__global__ __launch_bounds__(256) void k_gemm(const bf16* __restrict__ A,
    const bf16* __restrict__ Bt, const float* __restrict__ bias,
    void* __restrict__ Cv, int M, int N, int K, int out_mode,
    const int* __restrict__ flagp) {
  __shared__ bf16 sA[128][40];
  __shared__ bf16 sB[128][40];
  const int t = threadIdx.x;
  const int m0 = blockIdx.x * 128, n0 = blockIdx.y * 128;
  const int wave = t >> 6, lane = t & 63, quad = lane >> 4, l16 = lane & 15;
  const int wm = (wave >> 1) * 64, wn = (wave & 1) * 64;
  const int srow = t >> 1, sseg = (t & 1) * 16;
  const bf16* Ap = A + (size_t)(m0 + srow) * K + sseg;
  const bf16* Bp = Bt + (size_t)(n0 + srow) * K + sseg;
  f32x4 acc[4][4];
  f32x4 zero = {0.f, 0.f, 0.f, 0.f};
#pragma unroll
  for (int i = 0; i < 4; i++)
#pragma unroll
    for (int j = 0; j < 4; j++) acc[i][j] = zero;

  for (int k0 = 0; k0 < K; k0 += 32) {
    *(bf16x8*)&sA[srow][sseg]     = *(const bf16x8*)(Ap + k0);
    *(bf16x8*)&sA[srow][sseg + 8] = *(const bf16x8*)(Ap + k0 + 8);
    *(bf16x8*)&sB[srow][sseg]     = *(const bf16x8*)(Bp + k0);
    *(bf16x8*)&sB[srow][sseg + 8] = *(const bf16x8*)(Bp + k0 + 8);
    __syncthreads();
    bf16x8 af[4], bfr[4];
#pragma unroll
    for (int i = 0; i < 4; i++) af[i]  = *(const bf16x8*)&sA[wm + i * 16 + l16][quad * 8];
#pragma unroll
    for (int j = 0; j < 4; j++) bfr[j] = *(const bf16x8*)&sB[wn + j * 16 + l16][quad * 8];
#pragma unroll
    for (int i = 0; i < 4; i++)
#pragma unroll
      for (int j = 0; j < 4; j++)
        acc[i][j] = __builtin_amdgcn_mfma_f32_16x16x32_bf16(af[i], bfr[j], acc[i][j], 0, 0, 0);
    __syncthreads();
  }
  const bool obf = (out_mode != 0) && (*flagp != 0);
#pragma unroll
  for (int i = 0; i < 4; i++) {
#pragma unroll
    for (int j = 0; j < 4; j++) {
      int col = n0 + wn + j * 16 + l16;
      float bv = bias[col];
#pragma unroll
      for (int r = 0; r < 4; r++) {
        int row = m0 + wm + i * 16 + quad * 4 + r;
        float v = acc[i][j][r] + bv;
        if (obf) ((bf16*)Cv)[(size_t)row * N + col] = (bf16)v;
        else     ((float*)Cv)[(size_t)row * N + col] = v;
      }
    }
  }
}

// ---------------- focus scale: sqrt(sum relu(t)^2 / sum relu(t)^6) per (b,head) ----------------
__global__ __launch_bounds__(256) void k_focus(const float* __restrict__ X,
    float* __restrict__ scale, int nh, int W) {
  int g = blockIdx.x;
  int b = g / nh, h = g - b * nh;
  const float* base = X + (size_t)b * 1024 * W + h * 96;
  float s2 = 0.f, s6 = 0.f;
  for (int i = threadIdx.x; i < 1024 * 96; i += 256) {
    int n = i / 96, d = i - n * 96;
    float t = fmaxf(base[(size_t)n * W + d], 0.f);
    float t2 = t * t;
    s2 += t2;
    s6 += t2 * t2 * t2;
  }
  __shared__ float r2[256], r6[256];
  r2[threadIdx.x] = s2; r6[threadIdx.x] = s6;
  __syncthreads();
  for (int s = 128; s > 0; s >>= 1) {
    if ((int)threadIdx.x < s) {
      r2[threadIdx.x] += r2[threadIdx.x + s];
      r6[threadIdx.x] += r6[threadIdx.x + s];
    }
    __syncthreads();
  }
  if (threadIdx.x == 0) scale[g] = sqrtf(r2[0] / r6[0]);
}

// ---------------- qf = bf16(scale * relu(q)^3) ----------------
__global__ void k_qf(const float* __restrict__ Q, const float* __restrict__ scq,
                     bf16* __restrict__ QF) {
  int i = blockIdx.x * 256 + threadIdx.x;      // over 37748736/4 float4s
  if (i >= 9437184) return;
  int col = (i % 288) * 4;                     // 1152/4 = 288 float4 per row
  int b = i / 294912;                          // 1024*288 per batch
  float sc = scq[b * 12 + col / 96];
  float4 q = ((const float4*)Q)[i];
  bf16x4 o;
  float t;
  t = fmaxf(q.x, 0.f); o[0] = (bf16)(sc * t * t * t);
  t = fmaxf(q.y, 0.f); o[1] = (bf16)(sc * t * t * t);
  t = fmaxf(q.z, 0.f); o[2] = (bf16)(sc * t * t * t);
  t = fmaxf(q.w, 0.f); o[3] = (bf16)(sc * t * t * t);
  *(bf16x4*)(QF + (size_t)i * 4) = o;
}

// ---------------- kv einsum: KVT[b,kv][d][e] = scale_k * sum_n relu(k[n,e])^3 * v[n,d] ----------------
// (stored TRANSPOSED + bf16, ready as MFMA B-operand for the attn GEMM)
__global__ __launch_bounds__(256) void k_kvein(const float* __restrict__ KVP,
    const float* __restrict__ sck, bf16* __restrict__ KVT) {
  int g = blockIdx.x;                                  // b*4+kv
  const float* kbase = KVP + (size_t)(g >> 2) * 1024 * 768 + (g & 3) * 96;
  const float* vbase = kbase + 384;
  __shared__ float sk[32][96];
  __shared__ float sv[32][96];
  int ty = threadIdx.x >> 4, tx = threadIdx.x & 15;    // 16x16; each owns 6x6
  float acc[6][6];
#pragma unroll
  for (int i = 0; i < 6; i++)
#pragma unroll
    for (int j = 0; j < 6; j++) acc[i][j] = 0.f;
  for (int nc = 0; nc < 1024; nc += 32) {
    __syncthreads();
    for (int i = threadIdx.x; i < 32 * 96; i += 256) {
      int n = i / 96, d = i - n * 96;
      float kvv = fmaxf(kbase[(size_t)(nc + n) * 768 + d], 0.f);
      sk[n][d] = kvv * kvv * kvv;
      sv[n][d] = vbase[(size_t)(nc + n) * 768 + d];
    }
    __syncthreads();
#pragma unroll 4
    for (int n = 0; n < 32; n++) {
      float kr[6], vr[6];
#pragma unroll
      for (int i = 0; i < 6; i++) kr[i] = sk[n][ty * 6 + i];
#pragma unroll
      for (int j = 0; j < 6; j++) vr[j] = sv[n][tx * 6 + j];
#pragma unroll
      for (int i = 0; i < 6; i++)
#pragma unroll
        for (int j = 0; j < 6; j++) acc[i][j] += kr[i] * vr[j];
    }
  }
  float sc = sck[g];
  bf16* out = KVT + (size_t)g * 9216;
#pragma unroll
  for (int i = 0; i < 6; i++)
#pragma unroll
    for (int j = 0; j < 6; j++)
      out[(tx * 6 + j) * 96 + (ty * 6 + i)] = (bf16)(sc * acc[i][j]);   // [d][e]
}

// ---------------- depthwise 3x3 conv on 32x32 latent grid ----------------
__global__ void k_dwc(const float* __restrict__ KVP, const float* __restrict__ pw,
                      const float* __restrict__ pb, float* __restrict__ VD) {
  int idx = blockIdx.x * 256 + threadIdx.x;            // [B][KV][1024][96]
  if (idx >= 32 * 4 * 1024 * 96) return;
  int d  = idx % 96;
  int n  = (idx / 96) & 1023;
  int kv = (idx / (96 * 1024)) & 3;
  int b  = idx / (96 * 1024 * 4);
  int y = n >> 5, x = n & 31;
  int c = kv * 96 + d;
  const float* w = pw + c * 9;
  float acc = pb[c];
  const float* vb = KVP + (size_t)b * 1024 * 768 + 384 + c;
#pragma unroll
  for (int dy = -1; dy <= 1; dy++) {
    int yy = y + dy;
    if (yy < 0 || yy >= 32) continue;
#pragma unroll
    for (int dx = -1; dx <= 1; dx++) {
      int xx = x + dx;
      if (xx < 0 || xx >= 32) continue;
      acc += w[(dy + 1) * 3 + (dx + 1)] * vb[(size_t)((yy << 5) + xx) * 768];
    }
  }
  VD[idx] = acc;
}

// ---------------- attn: OC[b,n,h*96+d] = qf[b,h] @ kv[b,h%4] + vdwc[b,h%4] ----------------
__global__ __launch_bounds__(256) void k_attn(const bf16* __restrict__ QF,
    const bf16* __restrict__ KVT, const float* __restrict__ VD,
    bf16* __restrict__ OC) {
  int bh = blockIdx.x;
  int b = bh / 12, h = bh - b * 12;
  int kvh = h & 3;                    // jnp.tile -> head h uses kv-head h % 4
  int n0 = blockIdx.y * 64;
  __shared__ bf16 sQ[64][104];        // stride 208 B (16B-aligned, padded)
  __shared__ bf16 sKV[96][104];       // sKV[d][e]
  int t = threadIdx.x;
  const bf16* qsrc = QF + (size_t)(b * 1024 + n0) * 1152 + h * 96;
  for (int i = t; i < 64 * 12; i += 256) {
    int row = i / 12, seg = (i - row * 12) * 8;
    *(bf16x8*)&sQ[row][seg] = *(const bf16x8*)(qsrc + (size_t)row * 1152 + seg);
  }
  const bf16* kvsrc = KVT + (size_t)(b * 4 + kvh) * 9216;
  for (int i = t; i < 96 * 12; i += 256) {
    int row = i / 12, seg = (i - row * 12) * 8;
    *(bf16x8*)&sKV[row][seg] = *(const bf16x8*)(kvsrc + row * 96 + seg);
  }
  __syncthreads();
  int wave = t >> 6, lane = t & 63, quad = lane >> 4, l16 = lane & 15;
  f32x4 acc[6];
  f32x4 zero = {0.f, 0.f, 0.f, 0.f};
#pragma unroll
  for (int j = 0; j < 6; j++) acc[j] = zero;
#pragma unroll
  for (int k0 = 0; k0 < 96; k0 += 32) {
    bf16x8 a = *(const bf16x8*)&sQ[wave * 16 + l16][k0 + quad * 8];
#pragma unroll
    for (int j = 0; j < 6; j++) {
      bf16x8 bb = *(const bf16x8*)&sKV[j * 16 + l16][k0 + quad * 8];
      acc[j] = __builtin_amdgcn_mfma_f32_16x16x32_bf16(a, bb, acc[j], 0, 0, 0);
    }
  }
  const float* vd = VD + ((size_t)(b * 4 + kvh) * 1024 + n0) * 96;
  bf16* oc = OC + (size_t)(b * 1024 + n0) * 1152 + h * 96;
#pragma unroll
  for (int j = 0; j < 6; j++) {
    int col = j * 16 + l16;
#pragma unroll
    for (int r = 0; r < 4; r++) {
      int row = wave * 16 + quad * 4 + r;
      float v = acc[j][r] + vd[(size_t)row * 96 + col];
      oc[(size_t)row * 1152 + col] = (bf16)v;
    }
  }
}

// ---------------- launch ----------------
extern "C" void kernel_launch(void* const* d_in, const int* in_sizes, int n_in,
                              void* d_out, int out_size, void* d_ws, size_t ws_size,
                              hipStream_t stream) {
  (void)in_sizes; (void)n_in; (void)out_size; (void)ws_size;
  const void* x      = d_in[0];
  const void* wq_w   = d_in[1];
  const void* wq_b   = d_in[2];
  const void* wkv_w  = d_in[3];
  const void* wkv_b  = d_in[4];
  const void* dwc_w  = d_in[5];
  const void* dwc_b  = d_in[6];
  const void* proj_w = d_in[7];
  const void* proj_b = d_in[8];

  char* ws = (char*)d_ws;
  size_t off = 0;
  auto alloc = [&](size_t bytes) -> void* {
    void* p = ws + off;
    off = (off + bytes + 255) & ~(size_t)255;
    return p;
  };
  int*   flag   = (int*)  alloc(256);
  float* pbuf   = (float*)alloc((size_t)6912 * 4);
  bf16*  wq_t   = (bf16*) alloc((size_t)1152 * 1152 * 2);
  bf16*  wkv_t  = (bf16*) alloc((size_t)768 * 1152 * 2);
  bf16*  proj_t = (bf16*) alloc((size_t)1152 * 1152 * 2);
  bf16*  xb     = (bf16*) alloc((size_t)37748736 * 2);   // x bf16; reused as out_comb
  float* q_raw  = (float*)alloc((size_t)37748736 * 4);
  float* kvp    = (float*)alloc((size_t)32 * 1024 * 768 * 4);
  bf16*  qf     = (bf16*) alloc((size_t)37748736 * 2);
  bf16*  kvt    = (bf16*) alloc((size_t)128 * 9216 * 2);
  float* vdwc   = (float*)alloc((size_t)32 * 4 * 1024 * 96 * 4);
  float* scq    = (float*)alloc(384 * 4);
  float* sck    = (float*)alloc(128 * 4);

  k_detect<<<1, 256, 0, stream>>>((const unsigned int*)x, flag);
  k_prep<<<27, 256, 0, stream>>>(wq_b, wkv_b, dwc_w, dwc_b, proj_b, pbuf, flag);
  k_transpose<<<dim3(36, 36), 256, 0, stream>>>(wq_w, wq_t, 1152, 1152, flag);
  k_transpose<<<dim3(24, 36), 256, 0, stream>>>(wkv_w, wkv_t, 1152, 768, flag);
  k_transpose<<<dim3(36, 36), 256, 0, stream>>>(proj_w, proj_t, 1152, 1152, flag);
  k_ingest<<<147456, 256, 0, stream>>>(x, xb, flag);

  // q = x @ wq + b        (fp32 out: focus needs full precision before cubing)
  k_gemm<<<dim3(256, 9), 256, 0, stream>>>(xb, wq_t, pbuf + 0, (void*)q_raw,
                                           32768, 1152, 1152, 0, flag);
  // kvp = x @ wkv + b
  k_gemm<<<dim3(256, 6), 256, 0, stream>>>(xb, wkv_t, pbuf + 1152, (void*)kvp,
                                           32768, 768, 1152, 0, flag);

  k_focus<<<384, 256, 0, stream>>>(q_raw, scq, 12, 1152);   // per (b,h)
  k_focus<<<128, 256, 0, stream>>>(kvp, sck, 4, 768);       // per (b,kv): k is cols [0,384)

  k_qf<<<36864, 256, 0, stream>>>(q_raw, scq, qf);
  k_kvein<<<128, 256, 0, stream>>>(kvp, sck, kvt);
  k_dwc<<<49152, 256, 0, stream>>>(kvp, pbuf + 1920, pbuf + 5376, vdwc);
  k_attn<<<dim3(384, 16), 256, 0, stream>>>(qf, kvt, vdwc, xb /* out_comb */);

  // final: out = out_comb @ proj + b  -> d_out (dtype per detected flag)
  k_gemm<<<dim3(256, 9), 256, 0, stream>>>(xb, proj_t, pbuf + 5760, d_out,
                                           32768, 1152, 1152, 1, flag);
}

// Round 2
// 1280.155 us; speedup vs baseline: 1.1758x; 1.1758x over previous
//
#include <hip/hip_runtime.h>

typedef __bf16 bf16;
typedef __bf16 bf16x8 __attribute__((ext_vector_type(8)));
typedef __bf16 bf16x4 __attribute__((ext_vector_type(4)));
typedef float  f32x4  __attribute__((ext_vector_type(4)));

// Problem constants: B=32, N=1024, DIM=1152, H=12, KV=4, D=96, G=3, P=3, LS=32

static __device__ __forceinline__ float load_any(const void* p, size_t i, int isbf) {
  return isbf ? (float)((const bf16*)p)[i] : ((const float*)p)[i];
}

// async global->LDS, 16 bytes per lane. LDS dest is wave-uniform base + lane*16:
// callers MUST compute l = lds_base + lane*16 in wave-lane order (no padding).
static __device__ __forceinline__ void cp16(const bf16* g, bf16* l) {
  __builtin_amdgcn_global_load_lds(
      (const __attribute__((address_space(1))) void*)g,
      (__attribute__((address_space(3))) void*)l, 16, 0, 0);
}

// ---------------- dtype detect ----------------
__global__ void k_detect(const unsigned int* __restrict__ x, int* __restrict__ flag) {
  __shared__ int cnt[256];
  unsigned int w = x[(size_t)threadIdx.x * 65536u + 123u];
  unsigned int lo = w & 0xffffu;
  int e = (int)((lo >> 7) & 0xffu);
  cnt[threadIdx.x] = (lo == 0u) || (e >= 100 && e <= 140);
  __syncthreads();
  for (int s = 128; s > 0; s >>= 1) {
    if ((int)threadIdx.x < s) cnt[threadIdx.x] += cnt[threadIdx.x + s];
    __syncthreads();
  }
  if (threadIdx.x == 0) *flag = (cnt[0] >= 128) ? 1 : 0;
}

// ---------------- small params -> fp32 ----------------
// pbuf: [0,1152) wq_b | [1152,1920) wkv_b | [1920,5376) dwc_w | [5376,5760) dwc_b | [5760,6912) proj_b
__global__ void k_prep(const void* wq_b, const void* wkv_b, const void* dwc_w,
                       const void* dwc_b, const void* proj_b,
                       float* __restrict__ pbuf, const int* __restrict__ flagp) {
  int isbf = *flagp;
  int i = blockIdx.x * 256 + threadIdx.x;
  if (i >= 6912) return;
  float v;
  if (i < 1152)      v = load_any(wq_b,   i,        isbf);
  else if (i < 1920) v = load_any(wkv_b,  i - 1152, isbf);
  else if (i < 5376) v = load_any(dwc_w,  i - 1920, isbf);
  else if (i < 5760) v = load_any(dwc_b,  i - 5376, isbf);
  else               v = load_any(proj_b, i - 5760, isbf);
  pbuf[i] = v;
}

// ---------------- weight transpose -> bf16 [out][in] ----------------
__global__ __launch_bounds__(256) void k_transpose(const void* __restrict__ in,
    bf16* __restrict__ out, int R, int C, const int* __restrict__ flagp) {
  int isbf = *flagp;
  __shared__ bf16 tile[32][33];
  int c0 = blockIdx.x * 32, r0 = blockIdx.y * 32;
  int tx = threadIdx.x & 31, ty = threadIdx.x >> 5;
  for (int i = ty; i < 32; i += 8) {
    int r = r0 + i, c = c0 + tx;
    float v = (r < R && c < C) ? load_any(in, (size_t)r * C + c, isbf) : 0.f;
    tile[i][tx] = (bf16)v;
  }
  __syncthreads();
  for (int i = ty; i < 32; i += 8) {
    int c = c0 + i, r = r0 + tx;
    if (c < C && r < R) out[(size_t)c * R + r] = tile[tx][i];
  }
}

// ---------------- x ingest -> bf16 (fp32 mode only; bf16 mode reads x directly) ----------------
__global__ void k_ingest(const void* __restrict__ x, bf16* __restrict__ xb,
                         const int* __restrict__ flagp) {
  if (*flagp) return;   // bf16 input: GEMMs read x directly
  size_t i = ((size_t)blockIdx.x * 256 + threadIdx.x) * 8;
  if (i >= (size_t)37748736) return;
  const float4* xf = (const float4*)((const float*)x + i);
  float4 a = xf[0], b = xf[1];
  bf16x8 o = {(bf16)a.x, (bf16)a.y, (bf16)a.z, (bf16)a.w,
              (bf16)b.x, (bf16)b.y, (bf16)b.z, (bf16)b.w};
  *(bf16x8*)(xb + i) = o;
}

// ---------------- MFMA GEMM: C[M,N] = A[M,K] @ Bt[N,K]^T + bias ----------------
// m97 structure: 128x128 tile, BK=32, global_load_lds width=16 into UNPADDED
// [128][32] LDS (async-copy requires contiguous lane order; no padding).
// 4 waves, each a 64x64 quadrant of 4x4 16x16x32 mfma.
__global__ __launch_bounds__(256) void k_gemm(const bf16* __restrict__ A,
    const bf16* __restrict__ Aalt, int asel,
    const bf16* __restrict__ Bt, const float* __restrict__ bias,
    void* __restrict__ Cv, int M, int N, int K, int out_mode,
    const int* __restrict__ flagp) {
  __shared__ bf16 sA[128 * 32];
  __shared__ bf16 sB[128 * 32];
  const int t = threadIdx.x;
  const int m0 = blockIdx.x * 128, n0 = blockIdx.y * 128;
  const int wave = t >> 6, lane = t & 63, quad = lane >> 4, l16 = lane & 15;
  const int wm = (wave >> 1) * 64, wn = (wave & 1) * 64;
  const int flg = *flagp;
  const bf16* Asrc = (asel && flg) ? Aalt : A;
  // staging: wave w covers rows [w*32, w*32+32); per issue `it` rows w*32+it*16+(lane>>2),
  // col = (lane&3)*8 elems. LDS slot = row*32+col = wave_base + lane*8 elems (lane*16 B). ✓
  const int srow_base = wave * 32 + (lane >> 2);
  const int scol = (lane & 3) * 8;
  f32x4 acc[4][4];
  f32x4 zero = {0.f, 0.f, 0.f, 0.f};
#pragma unroll
  for (int i = 0; i < 4; i++)
#pragma unroll
    for (int j = 0; j < 4; j++) acc[i][j] = zero;

  for (int k0 = 0; k0 < K; k0 += 32) {
#pragma unroll
    for (int it = 0; it < 2; it++) {
      int row = srow_base + it * 16;
      cp16(Asrc + (size_t)(m0 + row) * K + k0 + scol, sA + row * 32 + scol);
      cp16(Bt   + (size_t)(n0 + row) * K + k0 + scol, sB + row * 32 + scol);
    }
    __syncthreads();   // compiler emits s_waitcnt vmcnt(0) before s_barrier -> LDS writes visible
    bf16x8 af[4], bfr[4];
#pragma unroll
    for (int i = 0; i < 4; i++) af[i]  = *(const bf16x8*)&sA[(wm + i * 16 + l16) * 32 + quad * 8];
#pragma unroll
    for (int j = 0; j < 4; j++) bfr[j] = *(const bf16x8*)&sB[(wn + j * 16 + l16) * 32 + quad * 8];
#pragma unroll
    for (int i = 0; i < 4; i++)
#pragma unroll
      for (int j = 0; j < 4; j++)
        acc[i][j] = __builtin_amdgcn_mfma_f32_16x16x32_bf16(af[i], bfr[j], acc[i][j], 0, 0, 0);
    __syncthreads();
  }
  const bool obf = (out_mode != 0) && (flg != 0);
#pragma unroll
  for (int i = 0; i < 4; i++) {
#pragma unroll
    for (int j = 0; j < 4; j++) {
      int col = n0 + wn + j * 16 + l16;
      float bv = bias[col];
#pragma unroll
      for (int r = 0; r < 4; r++) {
        int row = m0 + wm + i * 16 + quad * 4 + r;
        float v = acc[i][j][r] + bv;
        if (obf) ((bf16*)Cv)[(size_t)row * N + col] = (bf16)v;
        else     ((float*)Cv)[(size_t)row * N + col] = v;
      }
    }
  }
}

// ---------------- focus scale: sqrt(sum relu^2 / sum relu^6) per (b,head) ----------------
__global__ __launch_bounds__(256) void k_focus(const float* __restrict__ X,
    float* __restrict__ scale, int nh, int W) {
  int g = blockIdx.x;
  int b = g / nh, h = g - b * nh;
  const float* base = X + (size_t)b * 1024 * W + h * 96;
  float s2 = 0.f, s6 = 0.f;
  for (int i = threadIdx.x; i < 1024 * 96; i += 256) {
    int n = i / 96, d = i - n * 96;
    float t = fmaxf(base[(size_t)n * W + d], 0.f);
    float t2 = t * t;
    s2 += t2;
    s6 += t2 * t2 * t2;
  }
  __shared__ float r2[256], r6[256];
  r2[threadIdx.x] = s2; r6[threadIdx.x] = s6;
  __syncthreads();
  for (int s = 128; s > 0; s >>= 1) {
    if ((int)threadIdx.x < s) {
      r2[threadIdx.x] += r2[threadIdx.x + s];
      r6[threadIdx.x] += r6[threadIdx.x + s];
    }
    __syncthreads();
  }
  if (threadIdx.x == 0) scale[g] = sqrtf(r2[0] / r6[0]);
}

// ---------------- qf = bf16(scale * relu(q)^3) ----------------
__global__ void k_qf(const float* __restrict__ Q, const float* __restrict__ scq,
                     bf16* __restrict__ QF) {
  int i = blockIdx.x * 256 + threadIdx.x;      // float4 index
  if (i >= 9437184) return;
  int col = (i % 288) * 4;
  int b = i / 294912;
  float sc = scq[b * 12 + col / 96];
  float4 q = ((const float4*)Q)[i];
  bf16x4 o;
  float t;
  t = fmaxf(q.x, 0.f); o[0] = (bf16)(sc * t * t * t);
  t = fmaxf(q.y, 0.f); o[1] = (bf16)(sc * t * t * t);
  t = fmaxf(q.z, 0.f); o[2] = (bf16)(sc * t * t * t);
  t = fmaxf(q.w, 0.f); o[3] = (bf16)(sc * t * t * t);
  *(bf16x4*)(QF + (size_t)i * 4) = o;
}

// ---------------- kv einsum, split-K partials ----------------
// part[(g*8+c)][dk][e] = sum_{n in chunk c} relu(k[n,dk])^3 * v[n,e]
__global__ __launch_bounds__(256) void k_kvein_part(const float* __restrict__ KVP,
    float* __restrict__ part) {
  int blk = blockIdx.x;                 // g*8 + c
  int g = blk >> 3, c = blk & 7;
  const float* kbase = KVP + (size_t)(g >> 2) * 1024 * 768 + (g & 3) * 96
                     + (size_t)c * 128 * 768;
  const float* vbase = kbase + 384;
  __shared__ float sk[32][96];
  __shared__ float sv[32][96];
  int ty = threadIdx.x >> 4, tx = threadIdx.x & 15;
  float acc[6][6];
#pragma unroll
  for (int i = 0; i < 6; i++)
#pragma unroll
    for (int j = 0; j < 6; j++) acc[i][j] = 0.f;
  for (int nc = 0; nc < 128; nc += 32) {
    __syncthreads();
    for (int i = threadIdx.x; i < 32 * 96; i += 256) {
      int n = i / 96, d = i - n * 96;
      float kvv = fmaxf(kbase[(size_t)(nc + n) * 768 + d], 0.f);
      sk[n][d] = kvv * kvv * kvv;
      sv[n][d] = vbase[(size_t)(nc + n) * 768 + d];
    }
    __syncthreads();
#pragma unroll 4
    for (int n = 0; n < 32; n++) {
      float kr[6], vr[6];
#pragma unroll
      for (int i = 0; i < 6; i++) kr[i] = sk[n][ty * 6 + i];
#pragma unroll
      for (int j = 0; j < 6; j++) vr[j] = sv[n][tx * 6 + j];
#pragma unroll
      for (int i = 0; i < 6; i++)
#pragma unroll
        for (int j = 0; j < 6; j++) acc[i][j] += kr[i] * vr[j];
    }
  }
  float* out = part + (size_t)blk * 9216;
#pragma unroll
  for (int i = 0; i < 6; i++)
#pragma unroll
    for (int j = 0; j < 6; j++)
      out[(ty * 6 + i) * 96 + tx * 6 + j] = acc[i][j];   // [dk][e]
}

// reduce 8 partials, scale, store transposed bf16: KVT[g][e][dk]
__global__ void k_kvred(const float* __restrict__ part, const float* __restrict__ sck,
                        bf16* __restrict__ KVT) {
  int t = blockIdx.x * 256 + threadIdx.x;   // over 128*9216
  if (t >= 1179648) return;
  int g = t / 9216, r = t - g * 9216;
  int dk = r / 96, e = r - dk * 96;
  const float* p = part + (size_t)g * 8 * 9216 + r;
  float s = 0.f;
#pragma unroll
  for (int c = 0; c < 8; c++) s += p[(size_t)c * 9216];
  KVT[(size_t)g * 9216 + e * 96 + dk] = (bf16)(sck[g] * s);
}

// ---------------- depthwise 3x3 conv on 32x32 latent grid ----------------
__global__ void k_dwc(const float* __restrict__ KVP, const float* __restrict__ pw,
                      const float* __restrict__ pb, float* __restrict__ VD) {
  int idx = blockIdx.x * 256 + threadIdx.x;            // [B][KV][1024][96]
  if (idx >= 32 * 4 * 1024 * 96) return;
  int d  = idx % 96;
  int n  = (idx / 96) & 1023;
  int kv = (idx / (96 * 1024)) & 3;
  int b  = idx / (96 * 1024 * 4);
  int y = n >> 5, x = n & 31;
  int c = kv * 96 + d;
  const float* w = pw + c * 9;
  float acc = pb[c];
  const float* vb = KVP + (size_t)b * 1024 * 768 + 384 + c;
#pragma unroll
  for (int dy = -1; dy <= 1; dy++) {
    int yy = y + dy;
    if (yy < 0 || yy >= 32) continue;
#pragma unroll
    for (int dx = -1; dx <= 1; dx++) {
      int xx = x + dx;
      if (xx < 0 || xx >= 32) continue;
      acc += w[(dy + 1) * 3 + (dx + 1)] * vb[(size_t)((yy << 5) + xx) * 768];
    }
  }
  VD[idx] = acc;
}

// ---------------- attn: OC[b,n,h*96+d] = qf[b,h] @ kv[b,h%4] + vdwc[b,h%4] ----------------
__global__ __launch_bounds__(256) void k_attn(const bf16* __restrict__ QF,
    const bf16* __restrict__ KVT, const float* __restrict__ VD,
    bf16* __restrict__ OC) {
  int bh = blockIdx.x;
  int b = bh / 12, h = bh - b * 12;
  int kvh = h & 3;                    // jnp.tile -> head h uses kv-head h % 4
  int n0 = blockIdx.y * 64;
  __shared__ bf16 sQ[64][104];
  __shared__ bf16 sKV[96][104];
  int t = threadIdx.x;
  const bf16* qsrc = QF + (size_t)(b * 1024 + n0) * 1152 + h * 96;
  for (int i = t; i < 64 * 12; i += 256) {
    int row = i / 12, seg = (i - row * 12) * 8;
    *(bf16x8*)&sQ[row][seg] = *(const bf16x8*)(qsrc + (size_t)row * 1152 + seg);
  }
  const bf16* kvsrc = KVT + (size_t)(b * 4 + kvh) * 9216;
  for (int i = t; i < 96 * 12; i += 256) {
    int row = i / 12, seg = (i - row * 12) * 8;
    *(bf16x8*)&sKV[row][seg] = *(const bf16x8*)(kvsrc + row * 96 + seg);
  }
  __syncthreads();
  int wave = t >> 6, lane = t & 63, quad = lane >> 4, l16 = lane & 15;
  f32x4 acc[6];
  f32x4 zero = {0.f, 0.f, 0.f, 0.f};
#pragma unroll
  for (int j = 0; j < 6; j++) acc[j] = zero;
#pragma unroll
  for (int k0 = 0; k0 < 96; k0 += 32) {
    bf16x8 a = *(const bf16x8*)&sQ[wave * 16 + l16][k0 + quad * 8];
#pragma unroll
    for (int j = 0; j < 6; j++) {
      bf16x8 bb = *(const bf16x8*)&sKV[j * 16 + l16][k0 + quad * 8];
      acc[j] = __builtin_amdgcn_mfma_f32_16x16x32_bf16(a, bb, acc[j], 0, 0, 0);
    }
  }
  const float* vd = VD + ((size_t)(b * 4 + kvh) * 1024 + n0) * 96;
  bf16* oc = OC + (size_t)(b * 1024 + n0) * 1152 + h * 96;
#pragma unroll
  for (int j = 0; j < 6; j++) {
    int col = j * 16 + l16;
#pragma unroll
    for (int r = 0; r < 4; r++) {
      int row = wave * 16 + quad * 4 + r;
      float v = acc[j][r] + vd[(size_t)row * 96 + col];
      oc[(size_t)row * 1152 + col] = (bf16)v;
    }
  }
}

// ---------------- launch ----------------
extern "C" void kernel_launch(void* const* d_in, const int* in_sizes, int n_in,
                              void* d_out, int out_size, void* d_ws, size_t ws_size,
                              hipStream_t stream) {
  (void)in_sizes; (void)n_in; (void)out_size; (void)ws_size;
  const void* x      = d_in[0];
  const void* wq_w   = d_in[1];
  const void* wq_b   = d_in[2];
  const void* wkv_w  = d_in[3];
  const void* wkv_b  = d_in[4];
  const void* dwc_w  = d_in[5];
  const void* dwc_b  = d_in[6];
  const void* proj_w = d_in[7];
  const void* proj_b = d_in[8];

  char* ws = (char*)d_ws;
  size_t off = 0;
  auto alloc = [&](size_t bytes) -> void* {
    void* p = ws + off;
    off = (off + bytes + 255) & ~(size_t)255;
    return p;
  };
  int*   flag   = (int*)  alloc(256);
  float* pbuf   = (float*)alloc((size_t)6912 * 4);
  bf16*  wq_t   = (bf16*) alloc((size_t)1152 * 1152 * 2);
  bf16*  wkv_t  = (bf16*) alloc((size_t)768 * 1152 * 2);
  bf16*  proj_t = (bf16*) alloc((size_t)1152 * 1152 * 2);
  bf16*  xb     = (bf16*) alloc((size_t)37748736 * 2);   // x bf16 (fp32 mode); reused as out_comb
  float* q_raw  = (float*)alloc((size_t)37748736 * 4);   // q fp32; reused as kv partials
  float* kvp    = (float*)alloc((size_t)32 * 1024 * 768 * 4);
  bf16*  qf     = (bf16*) alloc((size_t)37748736 * 2);
  bf16*  kvt    = (bf16*) alloc((size_t)128 * 9216 * 2);
  float* vdwc   = (float*)alloc((size_t)32 * 4 * 1024 * 96 * 4);
  float* scq    = (float*)alloc(384 * 4);
  float* sck    = (float*)alloc(128 * 4);

  k_detect<<<1, 256, 0, stream>>>((const unsigned int*)x, flag);
  k_prep<<<27, 256, 0, stream>>>(wq_b, wkv_b, dwc_w, dwc_b, proj_b, pbuf, flag);
  k_transpose<<<dim3(36, 36), 256, 0, stream>>>(wq_w, wq_t, 1152, 1152, flag);
  k_transpose<<<dim3(24, 36), 256, 0, stream>>>(wkv_w, wkv_t, 1152, 768, flag);
  k_transpose<<<dim3(36, 36), 256, 0, stream>>>(proj_w, proj_t, 1152, 1152, flag);
  k_ingest<<<18432, 256, 0, stream>>>(x, xb, flag);

  const bf16* xbf = (const bf16*)x;   // used directly when input is bf16

  // q = x @ wq + b   (fp32 out: focus cubing needs full precision)
  k_gemm<<<dim3(256, 9), 256, 0, stream>>>(xb, xbf, 1, wq_t, pbuf + 0, (void*)q_raw,
                                           32768, 1152, 1152, 0, flag);
  // kvp = x @ wkv + b
  k_gemm<<<dim3(256, 6), 256, 0, stream>>>(xb, xbf, 1, wkv_t, pbuf + 1152, (void*)kvp,
                                           32768, 768, 1152, 0, flag);

  k_focus<<<384, 256, 0, stream>>>(q_raw, scq, 12, 1152);   // per (b,h)
  k_focus<<<128, 256, 0, stream>>>(kvp, sck, 4, 768);       // per (b,kv)

  k_qf<<<36864, 256, 0, stream>>>(q_raw, scq, qf);          // q_raw dead after this

  float* part = q_raw;                                       // alias: 37.75 MB < 151 MB
  k_kvein_part<<<1024, 256, 0, stream>>>(kvp, part);
  k_kvred<<<4608, 256, 0, stream>>>(part, sck, kvt);

  k_dwc<<<49152, 256, 0, stream>>>(kvp, pbuf + 1920, pbuf + 5376, vdwc);
  k_attn<<<dim3(384, 16), 256, 0, stream>>>(qf, kvt, vdwc, xb /* out_comb */);

  // final: out = out_comb @ proj + b  -> d_out (dtype per detected flag)
  k_gemm<<<dim3(256, 9), 256, 0, stream>>>(xb, nullptr, 0, proj_t, pbuf + 5760, d_out,
                                           32768, 1152, 1152, 1, flag);
}

// Round 3
// 971.185 us; speedup vs baseline: 1.5498x; 1.3181x over previous
//
#include <hip/hip_runtime.h>

typedef __bf16 bf16;
typedef __bf16 bf16x8 __attribute__((ext_vector_type(8)));
typedef __bf16 bf16x4 __attribute__((ext_vector_type(4)));
typedef float  f32x4  __attribute__((ext_vector_type(4)));

// Problem constants: B=32, N=1024, DIM=1152, H=12, KV=4, D=96, G=3, P=3, LS=32

static __device__ __forceinline__ float load_any(const void* p, size_t i, int isbf) {
  return isbf ? (float)((const bf16*)p)[i] : ((const float*)p)[i];
}

// async global->LDS, 16 bytes per lane. LDS dest is wave-uniform base + lane*16:
// callers MUST compute l = lds_base + lane*16 in wave-lane order (no padding).
static __device__ __forceinline__ void cp16(const bf16* g, bf16* l) {
  __builtin_amdgcn_global_load_lds(
      (const __attribute__((address_space(1))) void*)g,
      (__attribute__((address_space(3))) void*)l, 16, 0, 0);
}

// ---------------- dtype detect ----------------
__global__ void k_detect(const unsigned int* __restrict__ x, int* __restrict__ flag) {
  __shared__ int cnt[256];
  unsigned int w = x[(size_t)threadIdx.x * 65536u + 123u];
  unsigned int lo = w & 0xffffu;
  int e = (int)((lo >> 7) & 0xffu);
  cnt[threadIdx.x] = (lo == 0u) || (e >= 100 && e <= 140);
  __syncthreads();
  for (int s = 128; s > 0; s >>= 1) {
    if ((int)threadIdx.x < s) cnt[threadIdx.x] += cnt[threadIdx.x + s];
    __syncthreads();
  }
  if (threadIdx.x == 0) *flag = (cnt[0] >= 128) ? 1 : 0;
}

// ---------------- small params -> fp32; zero focus accumulators ----------------
// pbuf: [0,1152) wq_b | [1152,1920) wkv_b | [1920,5376) dwc_w | [5376,5760) dwc_b | [5760,6912) proj_b
__global__ void k_prep(const void* wq_b, const void* wkv_b, const void* dwc_w,
                       const void* dwc_b, const void* proj_b,
                       float* __restrict__ pbuf, float* __restrict__ acc,
                       const int* __restrict__ flagp) {
  int isbf = *flagp;
  int i = blockIdx.x * 256 + threadIdx.x;
  if (i < 1024) acc[i] = 0.f;
  if (i >= 6912) return;
  float v;
  if (i < 1152)      v = load_any(wq_b,   i,        isbf);
  else if (i < 1920) v = load_any(wkv_b,  i - 1152, isbf);
  else if (i < 5376) v = load_any(dwc_w,  i - 1920, isbf);
  else if (i < 5760) v = load_any(dwc_b,  i - 5376, isbf);
  else               v = load_any(proj_b, i - 5760, isbf);
  pbuf[i] = v;
}

// ---------------- weight transpose -> bf16 [out][in] ----------------
__global__ __launch_bounds__(256) void k_transpose(const void* __restrict__ in,
    bf16* __restrict__ out, int R, int C, const int* __restrict__ flagp) {
  int isbf = *flagp;
  __shared__ bf16 tile[32][33];
  int c0 = blockIdx.x * 32, r0 = blockIdx.y * 32;
  int tx = threadIdx.x & 31, ty = threadIdx.x >> 5;
  for (int i = ty; i < 32; i += 8) {
    int r = r0 + i, c = c0 + tx;
    float v = (r < R && c < C) ? load_any(in, (size_t)r * C + c, isbf) : 0.f;
    tile[i][tx] = (bf16)v;
  }
  __syncthreads();
  for (int i = ty; i < 32; i += 8) {
    int c = c0 + i, r = r0 + tx;
    if (c < C && r < R) out[(size_t)c * R + r] = tile[tx][i];
  }
}

// ---------------- x ingest -> bf16 (fp32 mode only; bf16 mode reads x directly) ----------------
__global__ void k_ingest(const void* __restrict__ x, bf16* __restrict__ xb,
                         const int* __restrict__ flagp) {
  if (*flagp) return;
  size_t i = ((size_t)blockIdx.x * 256 + threadIdx.x) * 8;
  if (i >= (size_t)37748736) return;
  const float4* xf = (const float4*)((const float*)x + i);
  float4 a = xf[0], b = xf[1];
  bf16x8 o = {(bf16)a.x, (bf16)a.y, (bf16)a.z, (bf16)a.w,
              (bf16)b.x, (bf16)b.y, (bf16)b.z, (bf16)b.w};
  *(bf16x8*)(xb + i) = o;
}

// ---------------- MFMA GEMM: C[M,N] = A[M,K] @ Bt[N,K]^T + bias ----------------
// m97 structure: 128x128 tile, BK=32, global_load_lds width=16 into UNPADDED
// [128][32] LDS. 4 waves, each a 64x64 quadrant of 4x4 16x16x32 mfma.
__global__ __launch_bounds__(256) void k_gemm(const bf16* __restrict__ A,
    const bf16* __restrict__ Aalt, int asel,
    const bf16* __restrict__ Bt, const float* __restrict__ bias,
    void* __restrict__ Cv, int M, int N, int K, int out_mode,
    const int* __restrict__ flagp) {
  __shared__ bf16 sA[128 * 32];
  __shared__ bf16 sB[128 * 32];
  const int t = threadIdx.x;
  const int m0 = blockIdx.x * 128, n0 = blockIdx.y * 128;
  const int wave = t >> 6, lane = t & 63, quad = lane >> 4, l16 = lane & 15;
  const int wm = (wave >> 1) * 64, wn = (wave & 1) * 64;
  const int flg = *flagp;
  const bf16* Asrc = (asel && flg) ? Aalt : A;
  const int srow_base = wave * 32 + (lane >> 2);
  const int scol = (lane & 3) * 8;
  f32x4 acc[4][4];
  f32x4 zero = {0.f, 0.f, 0.f, 0.f};
#pragma unroll
  for (int i = 0; i < 4; i++)
#pragma unroll
    for (int j = 0; j < 4; j++) acc[i][j] = zero;

  for (int k0 = 0; k0 < K; k0 += 32) {
#pragma unroll
    for (int it = 0; it < 2; it++) {
      int row = srow_base + it * 16;
      cp16(Asrc + (size_t)(m0 + row) * K + k0 + scol, sA + row * 32 + scol);
      cp16(Bt   + (size_t)(n0 + row) * K + k0 + scol, sB + row * 32 + scol);
    }
    __syncthreads();
    bf16x8 af[4], bfr[4];
#pragma unroll
    for (int i = 0; i < 4; i++) af[i]  = *(const bf16x8*)&sA[(wm + i * 16 + l16) * 32 + quad * 8];
#pragma unroll
    for (int j = 0; j < 4; j++) bfr[j] = *(const bf16x8*)&sB[(wn + j * 16 + l16) * 32 + quad * 8];
#pragma unroll
    for (int i = 0; i < 4; i++)
#pragma unroll
      for (int j = 0; j < 4; j++)
        acc[i][j] = __builtin_amdgcn_mfma_f32_16x16x32_bf16(af[i], bfr[j], acc[i][j], 0, 0, 0);
    __syncthreads();
  }
  const bool obf = (out_mode != 0) && (flg != 0);
#pragma unroll
  for (int i = 0; i < 4; i++) {
#pragma unroll
    for (int j = 0; j < 4; j++) {
      int col = n0 + wn + j * 16 + l16;
      float bv = bias[col];
#pragma unroll
      for (int r = 0; r < 4; r++) {
        int row = m0 + wm + i * 16 + quad * 4 + r;
        float v = acc[i][j][r] + bv;
        if (obf) ((bf16*)Cv)[(size_t)row * N + col] = (bf16)v;
        else     ((float*)Cv)[(size_t)row * N + col] = v;
      }
    }
  }
}

// ---------------- focus stage 1: per-(group,chunk) partial sums of relu^2 / relu^6 ----------------
// grid = ngroups*8; block handles 128 rows x 96 cols with 12 independent float4 loads/thread.
__global__ __launch_bounds__(256) void k_focus2(const float* __restrict__ X,
    float* __restrict__ acc, int accoff, int nh, int W) {
  int blk = blockIdx.x;
  int g = blk >> 3, c = blk & 7;
  int b = g / nh, h = g - b * nh;
  const float* base = X + ((size_t)b * 1024 + c * 128) * W + h * 96;
  float s2 = 0.f, s6 = 0.f;
#pragma unroll
  for (int it = 0; it < 12; it++) {
    int idx = it * 256 + threadIdx.x;
    int row = idx / 24, c4 = (idx - row * 24) * 4;
    float4 v = *(const float4*)(base + (size_t)row * W + c4);
    float t, t2;
    t = fmaxf(v.x, 0.f); t2 = t * t; s2 += t2; s6 += t2 * t2 * t2;
    t = fmaxf(v.y, 0.f); t2 = t * t; s2 += t2; s6 += t2 * t2 * t2;
    t = fmaxf(v.z, 0.f); t2 = t * t; s2 += t2; s6 += t2 * t2 * t2;
    t = fmaxf(v.w, 0.f); t2 = t * t; s2 += t2; s6 += t2 * t2 * t2;
  }
  __shared__ float r2[256], r6[256];
  r2[threadIdx.x] = s2; r6[threadIdx.x] = s6;
  __syncthreads();
  for (int s = 128; s > 0; s >>= 1) {
    if ((int)threadIdx.x < s) {
      r2[threadIdx.x] += r2[threadIdx.x + s];
      r6[threadIdx.x] += r6[threadIdx.x + s];
    }
    __syncthreads();
  }
  if (threadIdx.x == 0) {
    atomicAdd(&acc[(accoff + g) * 2],     r2[0]);
    atomicAdd(&acc[(accoff + g) * 2 + 1], r6[0]);
  }
}

// focus stage 2: scale[g] = sqrt(s2/s6)   (g in [0,512): 384 q-groups then 128 k-groups)
__global__ void k_scales(const float* __restrict__ acc, float* __restrict__ scale) {
  int i = blockIdx.x * 256 + threadIdx.x;
  if (i < 512) scale[i] = sqrtf(acc[i * 2] / acc[i * 2 + 1]);
}

// ---------------- qf = bf16(scale * relu(q)^3) ----------------
__global__ void k_qf(const float* __restrict__ Q, const float* __restrict__ scq,
                     bf16* __restrict__ QF) {
  int i = blockIdx.x * 256 + threadIdx.x;      // float4 index
  if (i >= 9437184) return;
  int col = (i % 288) * 4;
  int b = i / 294912;
  float sc = scq[b * 12 + col / 96];
  float4 q = ((const float4*)Q)[i];
  bf16x4 o;
  float t;
  t = fmaxf(q.x, 0.f); o[0] = (bf16)(sc * t * t * t);
  t = fmaxf(q.y, 0.f); o[1] = (bf16)(sc * t * t * t);
  t = fmaxf(q.z, 0.f); o[2] = (bf16)(sc * t * t * t);
  t = fmaxf(q.w, 0.f); o[3] = (bf16)(sc * t * t * t);
  *(bf16x4*)(QF + (size_t)i * 4) = o;
}

// ---------------- kv einsum, split-K partials ----------------
__global__ __launch_bounds__(256) void k_kvein_part(const float* __restrict__ KVP,
    float* __restrict__ part) {
  int blk = blockIdx.x;                 // g*8 + c
  int g = blk >> 3, c = blk & 7;
  const float* kbase = KVP + (size_t)(g >> 2) * 1024 * 768 + (g & 3) * 96
                     + (size_t)c * 128 * 768;
  const float* vbase = kbase + 384;
  __shared__ float sk[32][96];
  __shared__ float sv[32][96];
  int ty = threadIdx.x >> 4, tx = threadIdx.x & 15;
  float acc[6][6];
#pragma unroll
  for (int i = 0; i < 6; i++)
#pragma unroll
    for (int j = 0; j < 6; j++) acc[i][j] = 0.f;
  for (int nc = 0; nc < 128; nc += 32) {
    __syncthreads();
    for (int i = threadIdx.x; i < 32 * 96; i += 256) {
      int n = i / 96, d = i - n * 96;
      float kvv = fmaxf(kbase[(size_t)(nc + n) * 768 + d], 0.f);
      sk[n][d] = kvv * kvv * kvv;
      sv[n][d] = vbase[(size_t)(nc + n) * 768 + d];
    }
    __syncthreads();
#pragma unroll 4
    for (int n = 0; n < 32; n++) {
      float kr[6], vr[6];
#pragma unroll
      for (int i = 0; i < 6; i++) kr[i] = sk[n][ty * 6 + i];
#pragma unroll
      for (int j = 0; j < 6; j++) vr[j] = sv[n][tx * 6 + j];
#pragma unroll
      for (int i = 0; i < 6; i++)
#pragma unroll
        for (int j = 0; j < 6; j++) acc[i][j] += kr[i] * vr[j];
    }
  }
  float* out = part + (size_t)blk * 9216;
#pragma unroll
  for (int i = 0; i < 6; i++)
#pragma unroll
    for (int j = 0; j < 6; j++)
      out[(ty * 6 + i) * 96 + tx * 6 + j] = acc[i][j];   // [dk][e]
}

// reduce 8 partials, scale, store transposed bf16: KVT[g][e][dk]
__global__ void k_kvred(const float* __restrict__ part, const float* __restrict__ sck,
                        bf16* __restrict__ KVT) {
  int t = blockIdx.x * 256 + threadIdx.x;   // over 128*9216
  if (t >= 1179648) return;
  int g = t / 9216, r = t - g * 9216;
  int dk = r / 96, e = r - dk * 96;
  const float* p = part + (size_t)g * 8 * 9216 + r;
  float s = 0.f;
#pragma unroll
  for (int c = 0; c < 8; c++) s += p[(size_t)c * 9216];
  KVT[(size_t)g * 9216 + e * 96 + dk] = (bf16)(sck[g] * s);
}

// ---------------- depthwise 3x3 conv on 32x32 latent grid (bf16 out) ----------------
__global__ void k_dwc(const float* __restrict__ KVP, const float* __restrict__ pw,
                      const float* __restrict__ pb, bf16* __restrict__ VD) {
  int idx = blockIdx.x * 256 + threadIdx.x;            // [B][KV][1024][96]
  if (idx >= 32 * 4 * 1024 * 96) return;
  int d  = idx % 96;
  int n  = (idx / 96) & 1023;
  int kv = (idx / (96 * 1024)) & 3;
  int b  = idx / (96 * 1024 * 4);
  int y = n >> 5, x = n & 31;
  int c = kv * 96 + d;
  const float* w = pw + c * 9;
  float acc = pb[c];
  const float* vb = KVP + (size_t)b * 1024 * 768 + 384 + c;
#pragma unroll
  for (int dy = -1; dy <= 1; dy++) {
    int yy = y + dy;
    if (yy < 0 || yy >= 32) continue;
#pragma unroll
    for (int dx = -1; dx <= 1; dx++) {
      int xx = x + dx;
      if (xx < 0 || xx >= 32) continue;
      acc += w[(dy + 1) * 3 + (dx + 1)] * vb[(size_t)((yy << 5) + xx) * 768];
    }
  }
  VD[idx] = (bf16)acc;
}

// ---------------- attn: OC[b,n,h*96+d] = qf[b,h] @ kv[b,h%4] + vdwc[b,h%4] ----------------
__global__ __launch_bounds__(256) void k_attn(const bf16* __restrict__ QF,
    const bf16* __restrict__ KVT, const bf16* __restrict__ VD,
    bf16* __restrict__ OC) {
  int bh = blockIdx.x;
  int b = bh / 12, h = bh - b * 12;
  int kvh = h & 3;                    // jnp.tile -> head h uses kv-head h % 4
  int n0 = blockIdx.y * 64;
  __shared__ bf16 sQ[64][104];
  __shared__ bf16 sKV[96][104];
  int t = threadIdx.x;
  const bf16* qsrc = QF + (size_t)(b * 1024 + n0) * 1152 + h * 96;
  for (int i = t; i < 64 * 12; i += 256) {
    int row = i / 12, seg = (i - row * 12) * 8;
    *(bf16x8*)&sQ[row][seg] = *(const bf16x8*)(qsrc + (size_t)row * 1152 + seg);
  }
  const bf16* kvsrc = KVT + (size_t)(b * 4 + kvh) * 9216;
  for (int i = t; i < 96 * 12; i += 256) {
    int row = i / 12, seg = (i - row * 12) * 8;
    *(bf16x8*)&sKV[row][seg] = *(const bf16x8*)(kvsrc + row * 96 + seg);
  }
  __syncthreads();
  int wave = t >> 6, lane = t & 63, quad = lane >> 4, l16 = lane & 15;
  f32x4 acc[6];
  f32x4 zero = {0.f, 0.f, 0.f, 0.f};
#pragma unroll
  for (int j = 0; j < 6; j++) acc[j] = zero;
#pragma unroll
  for (int k0 = 0; k0 < 96; k0 += 32) {
    bf16x8 a = *(const bf16x8*)&sQ[wave * 16 + l16][k0 + quad * 8];
#pragma unroll
    for (int j = 0; j < 6; j++) {
      bf16x8 bb = *(const bf16x8*)&sKV[j * 16 + l16][k0 + quad * 8];
      acc[j] = __builtin_amdgcn_mfma_f32_16x16x32_bf16(a, bb, acc[j], 0, 0, 0);
    }
  }
  const bf16* vd = VD + ((size_t)(b * 4 + kvh) * 1024 + n0) * 96;
  bf16* oc = OC + (size_t)(b * 1024 + n0) * 1152 + h * 96;
#pragma unroll
  for (int j = 0; j < 6; j++) {
    int col = j * 16 + l16;
#pragma unroll
    for (int r = 0; r < 4; r++) {
      int row = wave * 16 + quad * 4 + r;
      float v = acc[j][r] + (float)vd[(size_t)row * 96 + col];
      oc[(size_t)row * 1152 + col] = (bf16)v;
    }
  }
}

// ---------------- launch ----------------
extern "C" void kernel_launch(void* const* d_in, const int* in_sizes, int n_in,
                              void* d_out, int out_size, void* d_ws, size_t ws_size,
                              hipStream_t stream) {
  (void)in_sizes; (void)n_in; (void)out_size; (void)ws_size;
  const void* x      = d_in[0];
  const void* wq_w   = d_in[1];
  const void* wq_b   = d_in[2];
  const void* wkv_w  = d_in[3];
  const void* wkv_b  = d_in[4];
  const void* dwc_w  = d_in[5];
  const void* dwc_b  = d_in[6];
  const void* proj_w = d_in[7];
  const void* proj_b = d_in[8];

  char* ws = (char*)d_ws;
  size_t off = 0;
  auto alloc = [&](size_t bytes) -> void* {
    void* p = ws + off;
    off = (off + bytes + 255) & ~(size_t)255;
    return p;
  };
  int*   flag   = (int*)  alloc(256);
  float* pbuf   = (float*)alloc((size_t)6912 * 4);
  float* facc   = (float*)alloc(1024 * 4);               // 512 groups x (s2,s6)
  float* scale  = (float*)alloc(512 * 4);                // [0,384) q | [384,512) k
  bf16*  wq_t   = (bf16*) alloc((size_t)1152 * 1152 * 2);
  bf16*  wkv_t  = (bf16*) alloc((size_t)768 * 1152 * 2);
  bf16*  proj_t = (bf16*) alloc((size_t)1152 * 1152 * 2);
  bf16*  xb     = (bf16*) alloc((size_t)37748736 * 2);   // x bf16 (fp32 mode); reused as out_comb
  float* q_raw  = (float*)alloc((size_t)37748736 * 4);   // q fp32; reused as kv partials
  float* kvp    = (float*)alloc((size_t)32 * 1024 * 768 * 4);
  bf16*  qf     = (bf16*) alloc((size_t)37748736 * 2);
  bf16*  kvt    = (bf16*) alloc((size_t)128 * 9216 * 2);
  bf16*  vdwc   = (bf16*) alloc((size_t)32 * 4 * 1024 * 96 * 2);

  k_detect<<<1, 256, 0, stream>>>((const unsigned int*)x, flag);
  k_prep<<<27, 256, 0, stream>>>(wq_b, wkv_b, dwc_w, dwc_b, proj_b, pbuf, facc, flag);
  k_transpose<<<dim3(36, 36), 256, 0, stream>>>(wq_w, wq_t, 1152, 1152, flag);
  k_transpose<<<dim3(24, 36), 256, 0, stream>>>(wkv_w, wkv_t, 1152, 768, flag);
  k_transpose<<<dim3(36, 36), 256, 0, stream>>>(proj_w, proj_t, 1152, 1152, flag);
  k_ingest<<<18432, 256, 0, stream>>>(x, xb, flag);

  const bf16* xbf = (const bf16*)x;

  // q = x @ wq + b   (fp32 out: focus cubing needs full precision)
  k_gemm<<<dim3(256, 9), 256, 0, stream>>>(xb, xbf, 1, wq_t, pbuf + 0, (void*)q_raw,
                                           32768, 1152, 1152, 0, flag);
  // kvp = x @ wkv + b
  k_gemm<<<dim3(256, 6), 256, 0, stream>>>(xb, xbf, 1, wkv_t, pbuf + 1152, (void*)kvp,
                                           32768, 768, 1152, 0, flag);

  k_focus2<<<3072, 256, 0, stream>>>(q_raw, facc, 0,   12, 1152);  // q groups
  k_focus2<<<1024, 256, 0, stream>>>(kvp,   facc, 384, 4,  768);   // k groups
  k_scales<<<2, 256, 0, stream>>>(facc, scale);

  k_qf<<<36864, 256, 0, stream>>>(q_raw, scale, qf);        // q_raw dead after this

  float* part = q_raw;                                       // alias: 37.75 MB < 151 MB
  k_kvein_part<<<1024, 256, 0, stream>>>(kvp, part);
  k_kvred<<<4608, 256, 0, stream>>>(part, scale + 384, kvt);

  k_dwc<<<49152, 256, 0, stream>>>(kvp, pbuf + 1920, pbuf + 5376, vdwc);
  k_attn<<<dim3(384, 16), 256, 0, stream>>>(qf, kvt, vdwc, xb /* out_comb */);

  // final: out = out_comb @ proj + b  -> d_out (dtype per detected flag)
  k_gemm<<<dim3(256, 9), 256, 0, stream>>>(xb, nullptr, 0, proj_t, pbuf + 5760, d_out,
                                           32768, 1152, 1152, 1, flag);
}